// Round 1
// baseline (364.454 us; speedup 1.0000x reference)
//
#include <hip/hip_runtime.h>
#include <math.h>

#define TPB 256

static constexpr int LL = 16;
static constexpr int KK = 2048;
static constexpr int NBATCH = 4;
static constexpr int NN = 4096;        // K*B
static constexpr int BBR = 8;          // (branch, batch) combos

// workspace layout in floats
static constexpr size_t OFF_XET  = 0;         // 4*4096*16 ; later reused as Ea_t[8][4096][16]
static constexpr size_t OFF_SET  = 262144;
static constexpr size_t OFF_LSE  = 524288;    // 8*4096
static constexpr size_t OFF_PAMX = 557056;    // 8*8*4096
static constexpr size_t OFF_PASM = 819200;    // 8*8*4096
static constexpr size_t OFF_PB   = 1081344;   // 8*8*4096*16
static constexpr size_t OFF_XHAT = 1081344;   // reuse of PB region (PB dead by then)
static constexpr size_t OFF_SHAT = 1605632;

// ---------------------------------------------------------------- prep
// Xet[b][n][m] = sum_l S[b,l,n]*W1x[l,m] ; Set[b][n][m] = sum_l X[b,l,n]*W1s[l,m]
__global__ __launch_bounds__(TPB) void prep_kernel(
    const float* __restrict__ X, const float* __restrict__ S,
    const float* __restrict__ W1x, const float* __restrict__ W1s,
    float* __restrict__ Xet, float* __restrict__ Set) {
  __shared__ float w1x[256], w1s[256];
  const int tid = threadIdx.x;
  w1x[tid] = W1x[tid];
  w1s[tid] = W1s[tid];
  __syncthreads();
  const int flat = blockIdx.x * TPB + tid;   // b*4096 + n
  const int b = flat >> 12, n = flat & 4095;
  float s[16], x[16];
#pragma unroll
  for (int l = 0; l < 16; ++l) {
    s[l] = S[(size_t)(b * 16 + l) * NN + n];
    x[l] = X[(size_t)(b * 16 + l) * NN + n];
  }
  float xe[16], se[16];
#pragma unroll
  for (int m = 0; m < 16; ++m) {
    float a0 = 0.f, a1 = 0.f;
#pragma unroll
    for (int l = 0; l < 16; ++l) {
      a0 = fmaf(s[l], w1x[l * 16 + m], a0);
      a1 = fmaf(x[l], w1s[l * 16 + m], a1);
    }
    xe[m] = a0;
    se[m] = a1;
  }
  float4* xo = (float4*)(Xet + (size_t)flat * 16);
  float4* so = (float4*)(Set + (size_t)flat * 16);
#pragma unroll
  for (int q = 0; q < 4; ++q) {
    xo[q] = make_float4(xe[q * 4], xe[q * 4 + 1], xe[q * 4 + 2], xe[q * 4 + 3]);
    so[q] = make_float4(se[q * 4], se[q * 4 + 1], se[q * 4 + 2], se[q * 4 + 3]);
  }
}

// ---------------------------------------------------------------- pass A
// per n: running max & sum of exp over an m-range (msplit partials)
__global__ __launch_bounds__(TPB) void passA_kernel(
    const float* __restrict__ Xet, const float* __restrict__ Set,
    float* __restrict__ pmx, float* __restrict__ psm) {
  const int nt = blockIdx.x;    // 0..7  n-tile (512 n)
  const int ms = blockIdx.y;    // 0..7  m-split (512 m)
  const int bbr = blockIdx.z;   // 0..7  br*4+b
  const int br = bbr >> 2, b = bbr & 3;
  const float* Et = (br ? Set : Xet) + (size_t)b * (NN * LL);
  const int tid = threadIdx.x;
  __shared__ float ebuf[256 * 20];

  float myE[2][16];
#pragma unroll
  for (int c = 0; c < 2; ++c) {
    const int n = nt * 512 + c * 256 + tid;
    const float4* p = (const float4*)(Et + (size_t)n * 16);
#pragma unroll
    for (int q = 0; q < 4; ++q) {
      float4 v = p[q];
      myE[c][q * 4 + 0] = v.x; myE[c][q * 4 + 1] = v.y;
      myE[c][q * 4 + 2] = v.z; myE[c][q * 4 + 3] = v.w;
    }
  }
  float mx[2] = {-INFINITY, -INFINITY};
  float sm[2] = {0.f, 0.f};

  for (int chunk = 0; chunk < 2; ++chunk) {
    const int m0 = ms * 512 + chunk * 256;
    __syncthreads();
    {
      const float4* p = (const float4*)(Et + (size_t)(m0 + tid) * 16);
      float* d = ebuf + tid * 20;
#pragma unroll
      for (int q = 0; q < 4; ++q) ((float4*)d)[q] = p[q];
    }
    __syncthreads();
    for (int mm = 0; mm < 256; ++mm) {
      const float* e = ebuf + mm * 20;
      float ee[16];
#pragma unroll
      for (int q = 0; q < 4; ++q) {
        float4 v = ((const float4*)e)[q];
        ee[q * 4 + 0] = v.x; ee[q * 4 + 1] = v.y;
        ee[q * 4 + 2] = v.z; ee[q * 4 + 3] = v.w;
      }
#pragma unroll
      for (int c = 0; c < 2; ++c) {
        float g0 = 0.f, g1 = 0.f;
#pragma unroll
        for (int q = 0; q < 8; ++q) g0 = fmaf(myE[c][q], ee[q], g0);
#pragma unroll
        for (int q = 8; q < 16; ++q) g1 = fmaf(myE[c][q], ee[q], g1);
        const float g = g0 + g1;
        if (g > mx[c]) {
          sm[c] = fmaf(sm[c], __expf(mx[c] - g), 1.0f);
          mx[c] = g;
        } else {
          sm[c] += __expf(g - mx[c]);
        }
      }
    }
  }
#pragma unroll
  for (int c = 0; c < 2; ++c) {
    const int n = nt * 512 + c * 256 + tid;
    const size_t o = (size_t)(ms * BBR + bbr) * NN + n;
    pmx[o] = mx[c];
    psm[o] = sm[c];
  }
}

// ---------------------------------------------------------------- reduce A -> lse
__global__ __launch_bounds__(TPB) void reduceA_kernel(
    const float* __restrict__ pmx, const float* __restrict__ psm,
    float* __restrict__ lse) {
  const int idx = blockIdx.x * TPB + threadIdx.x;  // bbr*4096 + n
  float M = -INFINITY;
#pragma unroll
  for (int ms = 0; ms < 8; ++ms) M = fmaxf(M, pmx[(size_t)ms * (BBR * NN) + idx]);
  float Ssum = 0.f;
#pragma unroll
  for (int ms = 0; ms < 8; ++ms)
    Ssum += psm[(size_t)ms * (BBR * NN) + idx] *
            __expf(pmx[(size_t)ms * (BBR * NN) + idx] - M);
  lse[idx] = M + logf(Ssum);
}

// ---------------------------------------------------------------- pass B
// Ea[l,m] partial over an n-range: sum_n exp(G[n,m]-lse[n]) * E[l,n]
__global__ __launch_bounds__(TPB) void passB_kernel(
    const float* __restrict__ Xet, const float* __restrict__ Set,
    const float* __restrict__ lse, float* __restrict__ pb) {
  const int mt = blockIdx.x;    // 0..7  m-tile (512 m)
  const int ns = blockIdx.y;    // 0..7  n-split (512 n)
  const int bbr = blockIdx.z;   // 0..7
  const int br = bbr >> 2, b = bbr & 3;
  const float* Et = (br ? Set : Xet) + (size_t)b * (NN * LL);
  const float* lsb = lse + (size_t)bbr * NN;
  const int tid = threadIdx.x;
  __shared__ float ebuf[256 * 20];
  __shared__ float lbuf[256];

  float myE[2][16];
#pragma unroll
  for (int c = 0; c < 2; ++c) {
    const int m = mt * 512 + c * 256 + tid;
    const float4* p = (const float4*)(Et + (size_t)m * 16);
#pragma unroll
    for (int q = 0; q < 4; ++q) {
      float4 v = p[q];
      myE[c][q * 4 + 0] = v.x; myE[c][q * 4 + 1] = v.y;
      myE[c][q * 4 + 2] = v.z; myE[c][q * 4 + 3] = v.w;
    }
  }
  float acc[2][16];
#pragma unroll
  for (int c = 0; c < 2; ++c)
#pragma unroll
    for (int q = 0; q < 16; ++q) acc[c][q] = 0.f;

  for (int chunk = 0; chunk < 2; ++chunk) {
    const int n0 = ns * 512 + chunk * 256;
    __syncthreads();
    {
      const float4* p = (const float4*)(Et + (size_t)(n0 + tid) * 16);
      float* d = ebuf + tid * 20;
#pragma unroll
      for (int q = 0; q < 4; ++q) ((float4*)d)[q] = p[q];
      lbuf[tid] = lsb[n0 + tid];
    }
    __syncthreads();
    for (int nn = 0; nn < 256; ++nn) {
      const float* e = ebuf + nn * 20;
      float ee[16];
#pragma unroll
      for (int q = 0; q < 4; ++q) {
        float4 v = ((const float4*)e)[q];
        ee[q * 4 + 0] = v.x; ee[q * 4 + 1] = v.y;
        ee[q * 4 + 2] = v.z; ee[q * 4 + 3] = v.w;
      }
      const float lv = lbuf[nn];
#pragma unroll
      for (int c = 0; c < 2; ++c) {
        float g0 = 0.f, g1 = 0.f;
#pragma unroll
        for (int q = 0; q < 8; ++q) g0 = fmaf(myE[c][q], ee[q], g0);
#pragma unroll
        for (int q = 8; q < 16; ++q) g1 = fmaf(myE[c][q], ee[q], g1);
        const float p = __expf((g0 + g1) - lv);
#pragma unroll
        for (int q = 0; q < 16; ++q) acc[c][q] = fmaf(p, ee[q], acc[c][q]);
      }
    }
  }
#pragma unroll
  for (int c = 0; c < 2; ++c) {
    const int m = mt * 512 + c * 256 + tid;
    float* dst = pb + ((size_t)(ns * BBR + bbr) * NN + m) * 16;
#pragma unroll
    for (int q = 0; q < 4; ++q)
      ((float4*)dst)[q] = make_float4(acc[c][q * 4], acc[c][q * 4 + 1],
                                      acc[c][q * 4 + 2], acc[c][q * 4 + 3]);
  }
}

// ---------------------------------------------------------------- reduce B -> Ea_t
__global__ __launch_bounds__(TPB) void reduceB_kernel(
    const float* __restrict__ pb, float* __restrict__ ea) {
  const int idx = blockIdx.x * TPB + threadIdx.x;  // float4 index, 0..131071
  const float4* p = (const float4*)pb;
  float4 a = p[idx];
#pragma unroll
  for (int ns = 1; ns < 8; ++ns) {
    float4 v = p[(size_t)ns * 131072 + idx];
    a.x += v.x; a.y += v.y; a.z += v.z; a.w += v.w;
  }
  ((float4*)ea)[idx] = a;
}

// ---------------------------------------------------------------- M-mix + assemble conv inputs
// M[(b,l,t), j] = sum_k Ea_t[b][k*32 + t*16 + l] * W2[k, j]
__global__ __launch_bounds__(TPB) void mmix_kernel(
    const float* __restrict__ Ea,
    const float* __restrict__ W2x, const float* __restrict__ W2s,
    const float* __restrict__ X, const float* __restrict__ S,
    float* __restrict__ Xhat, float* __restrict__ Shat) {
  const int jt = blockIdx.x;   // 0..31
  const int b = blockIdx.y;    // 0..3
  const int br = blockIdx.z;   // 0..1
  const float* W2 = br ? W2s : W2x;
  const float* A = Ea + (size_t)(br * 4 + b) * (NN * LL);
  __shared__ float ldsA[64 * 36];
  __shared__ float ldsW[64 * 64];
  const int tid = threadIdx.x;
  const int r = tid & 31, jq = tid >> 5;   // r = t*16+l, jq in 0..7
  const int j0 = jt * 64;
  float acc[8];
#pragma unroll
  for (int i = 0; i < 8; ++i) acc[i] = 0.f;

  for (int k0 = 0; k0 < KK; k0 += 64) {
    __syncthreads();
    {
      const float4* src = (const float4*)(A + (size_t)k0 * 32);
#pragma unroll
      for (int q = 0; q < 2; ++q) {
        const int f4 = tid * 2 + q;            // 0..511
        float4 v = src[f4];
        const int kkk = f4 >> 3;
        const int rr = (f4 & 7) * 4;
        *((float4*)(ldsA + kkk * 36 + rr)) = v;
      }
#pragma unroll
      for (int q = 0; q < 4; ++q) {
        const int f4 = q * 256 + tid;          // 0..1023
        const int kkk = f4 >> 4;
        const int jj = (f4 & 15) * 4;
        float4 v = *(const float4*)(W2 + (size_t)(k0 + kkk) * KK + j0 + jj);
        *((float4*)(ldsW + kkk * 64 + jj)) = v;
      }
    }
    __syncthreads();
#pragma unroll 4
    for (int kk2 = 0; kk2 < 64; ++kk2) {
      const float a = ldsA[kk2 * 36 + r];
      const float4 w0 = *(const float4*)(ldsW + kk2 * 64 + jq * 8);
      const float4 w1 = *(const float4*)(ldsW + kk2 * 64 + jq * 8 + 4);
      acc[0] = fmaf(a, w0.x, acc[0]);
      acc[1] = fmaf(a, w0.y, acc[1]);
      acc[2] = fmaf(a, w0.z, acc[2]);
      acc[3] = fmaf(a, w0.w, acc[3]);
      acc[4] = fmaf(a, w1.x, acc[4]);
      acc[5] = fmaf(a, w1.y, acc[5]);
      acc[6] = fmaf(a, w1.z, acc[6]);
      acc[7] = fmaf(a, w1.w, acc[7]);
    }
  }
  const int t = r >> 4, l = r & 15;
#pragma unroll
  for (int i = 0; i < 8; ++i) {
    const int j = j0 + jq * 8 + i;
    const int n = j * 2 + t;
    if (br == 0) {
      const float xv = X[(size_t)(b * 16 + l) * NN + n];
      Xhat[((size_t)(b * 32 + l) * KK + j) * 2 + t] = acc[i] * xv;
      Xhat[((size_t)(b * 32 + 16 + l) * KK + j) * 2 + t] = xv;
    } else {
      const float sv = S[(size_t)(b * 16 + l) * NN + n];
      const float pe = t ? cosf((float)j) : sinf((float)j);
      Shat[((size_t)(b * 32 + l) * KK + j) * 2 + t] = fmaf(acc[i], sv, pe);
      Shat[((size_t)(b * 32 + 16 + l) * KK + j) * 2 + t] = sv + pe;
    }
  }
}

// ---------------------------------------------------------------- 3x3 SAME conv, H=2048 W=2
__global__ __launch_bounds__(TPB) void conv_kernel(
    const float* __restrict__ Xhat, const float* __restrict__ Shat,
    const float* __restrict__ Wx, const float* __restrict__ Bx,
    const float* __restrict__ Ws, const float* __restrict__ Bs,
    float* __restrict__ out) {
  const int kt = blockIdx.x;   // 0..31 (64-row tiles)
  const int b = blockIdx.y;
  const int br = blockIdx.z;
  const float* In = (br ? Shat : Xhat) + (size_t)b * 32 * KK * 2;
  const float* Wt = br ? Ws : Wx;
  const float* Bi = br ? Bs : Bx;
  __shared__ float inT[32 * 66 * 2];     // [cin][66][2], halo rows
  __shared__ float wts[32 * 289];        // c*289 + cin*9 + tap (pad kills conflicts)
  const int tid = threadIdx.x;
  const int k0 = kt * 64;

  for (int f = tid; f < 32 * 288; f += TPB) {
    const int c = f / 288, rem = f % 288;
    wts[c * 289 + rem] = Wt[f];
  }
  for (int f = tid; f < 32 * 66 * 2; f += TPB) {
    const int ch = f / 132, rem = f % 132;
    const int kk = rem >> 1, t = rem & 1;
    const int kg = k0 - 1 + kk;
    inT[f] = (kg >= 0 && kg < KK) ? In[((size_t)ch * KK + kg) * 2 + t] : 0.f;
  }
  __syncthreads();

  const int c = tid >> 3, sub = tid & 7;
  const float bias = Bi[c];
  float acc0[8], acc1[8];
#pragma unroll
  for (int i = 0; i < 8; ++i) { acc0[i] = bias; acc1[i] = bias; }

  for (int cin = 0; cin < 32; ++cin) {
    const float* wp = wts + c * 289 + cin * 9;
    const float w00 = wp[0], w01 = wp[1], w02 = wp[2];
    const float w10 = wp[3], w11 = wp[4], w12 = wp[5];
    const float w20 = wp[6], w21 = wp[7], w22 = wp[8];
    const float* ip = inT + cin * 132;
#pragma unroll
    for (int i = 0; i < 8; ++i) {
      const int kl = sub + 8 * i;            // halo-local row of output k
      const float* q = ip + kl * 2;
      const float i00 = q[0], i01 = q[1];
      const float i10 = q[2], i11 = q[3];
      const float i20 = q[4], i21 = q[5];
      // t = 0: taps (dh, w-col 1..2)
      acc0[i] = fmaf(i00, w01, acc0[i]); acc0[i] = fmaf(i01, w02, acc0[i]);
      acc0[i] = fmaf(i10, w11, acc0[i]); acc0[i] = fmaf(i11, w12, acc0[i]);
      acc0[i] = fmaf(i20, w21, acc0[i]); acc0[i] = fmaf(i21, w22, acc0[i]);
      // t = 1: taps (dh, w-col 0..1)
      acc1[i] = fmaf(i00, w00, acc1[i]); acc1[i] = fmaf(i01, w01, acc1[i]);
      acc1[i] = fmaf(i10, w10, acc1[i]); acc1[i] = fmaf(i11, w11, acc1[i]);
      acc1[i] = fmaf(i20, w20, acc1[i]); acc1[i] = fmaf(i21, w21, acc1[i]);
    }
  }
#pragma unroll
  for (int i = 0; i < 8; ++i) {
    const int k = k0 + sub + 8 * i;
    const size_t o = ((size_t)(b * 64 + br * 32 + c) * KK + k) * 2;
    out[o] = acc0[i];
    out[o + 1] = acc1[i];
  }
}

// ---------------------------------------------------------------- launch
extern "C" void kernel_launch(void* const* d_in, const int* in_sizes, int n_in,
                              void* d_out, int out_size, void* d_ws, size_t ws_size,
                              hipStream_t stream) {
  (void)in_sizes; (void)n_in; (void)out_size; (void)ws_size;
  const float* X   = (const float*)d_in[0];
  const float* S   = (const float*)d_in[1];
  const float* W1x = (const float*)d_in[2];
  const float* W1s = (const float*)d_in[3];
  const float* W2x = (const float*)d_in[4];
  const float* W2s = (const float*)d_in[5];
  const float* Cwx = (const float*)d_in[6];
  const float* Cbx = (const float*)d_in[7];
  const float* Cws = (const float*)d_in[8];
  const float* Cbs = (const float*)d_in[9];
  float* out = (float*)d_out;
  float* ws = (float*)d_ws;

  float* Xet = ws + OFF_XET;
  float* Set = ws + OFF_SET;
  float* lse = ws + OFF_LSE;
  float* pmx = ws + OFF_PAMX;
  float* psm = ws + OFF_PASM;
  float* pb  = ws + OFF_PB;
  float* Ea  = ws + OFF_XET;   // reuse Xet+Set region
  float* Xh  = ws + OFF_XHAT;  // reuse PB region
  float* Sh  = ws + OFF_SHAT;

  hipLaunchKernelGGL(prep_kernel, dim3(NBATCH * NN / TPB), dim3(TPB), 0, stream,
                     X, S, W1x, W1s, Xet, Set);
  hipLaunchKernelGGL(passA_kernel, dim3(8, 8, 8), dim3(TPB), 0, stream,
                     Xet, Set, pmx, psm);
  hipLaunchKernelGGL(reduceA_kernel, dim3(BBR * NN / TPB), dim3(TPB), 0, stream,
                     pmx, psm, lse);
  hipLaunchKernelGGL(passB_kernel, dim3(8, 8, 8), dim3(TPB), 0, stream,
                     Xet, Set, lse, pb);
  hipLaunchKernelGGL(reduceB_kernel, dim3(BBR * NN * LL / 4 / TPB), dim3(TPB), 0, stream,
                     pb, Ea);
  hipLaunchKernelGGL(mmix_kernel, dim3(32, NBATCH, 2), dim3(TPB), 0, stream,
                     Ea, W2x, W2s, X, S, Xh, Sh);
  hipLaunchKernelGGL(conv_kernel, dim3(32, NBATCH, 2), dim3(TPB), 0, stream,
                     Xh, Sh, Cwx, Cbx, Cws, Cbs, out);
}

// Round 2
// 206.946 us; speedup vs baseline: 1.7611x; 1.7611x over previous
//
#include <hip/hip_runtime.h>
#include <math.h>

#define TPB 256

static constexpr int LL = 16;
static constexpr int KK = 2048;
static constexpr int NBATCH = 4;
static constexpr int NN = 4096;        // K*B
static constexpr int BBR = 8;          // (branch, batch) combos

// workspace layout in floats
static constexpr size_t OFF_EA  = 0;          // 8*4096*16 f32
static constexpr size_t OFF_EHL = 524288;     // 8*4096*32 bf16 (= 524288 f32 slots)
static constexpr size_t OFF_ET  = 1048576;    // 8*16*4096 bf16 (= 262144 f32 slots)
static constexpr size_t OFF_LSE = 1310720;    // 8*4096 f32
static constexpr size_t OFF_XH  = 524288;     // aliases EHL (dead after passB)
static constexpr size_t OFF_SH  = 1048576;    // aliases ET+LSE (dead after passB)

typedef unsigned short ushortT;
typedef __attribute__((ext_vector_type(8))) short short8v;
typedef __attribute__((ext_vector_type(4))) float f32x4;

__device__ __forceinline__ ushortT f2bf(float x) {
  union { float f; unsigned int u; } c; c.f = x;
  unsigned int u = c.u;
  return (ushortT)((u + 0x7FFFu + ((u >> 16) & 1u)) >> 16);
}
__device__ __forceinline__ float bf2f(ushortT h) {
  union { unsigned int u; float f; } c; c.u = ((unsigned int)h) << 16;
  return c.f;
}

// ---------------------------------------------------------------- prep
// E = einsum over L; emit bf16 split Ehl[bbr][n][32] = [hi(16)|lo(16)] and
// transposed Et[bbr][l][n] (hi only) for the PV A-operand.
__global__ __launch_bounds__(TPB) void prep_kernel(
    const float* __restrict__ X, const float* __restrict__ S,
    const float* __restrict__ W1x, const float* __restrict__ W1s,
    ushortT* __restrict__ Ehl, ushortT* __restrict__ Et) {
  __shared__ float w1x[256], w1s[256];
  __shared__ ushortT tl[16][272];
  const int tid = threadIdx.x;
  w1x[tid] = W1x[tid];
  w1s[tid] = W1s[tid];
  __syncthreads();
  const int n0 = blockIdx.x * 256;
  const int b = blockIdx.y;
  const int n = n0 + tid;
  float s[16], x[16];
#pragma unroll
  for (int l = 0; l < 16; ++l) {
    s[l] = S[(size_t)(b * 16 + l) * NN + n];
    x[l] = X[(size_t)(b * 16 + l) * NN + n];
  }
  float xe[16], se[16];
#pragma unroll
  for (int m = 0; m < 16; ++m) {
    float a0 = 0.f, a1 = 0.f;
#pragma unroll
    for (int l = 0; l < 16; ++l) {
      a0 = fmaf(s[l], w1x[l * 16 + m], a0);
      a1 = fmaf(x[l], w1s[l * 16 + m], a1);
    }
    xe[m] = a0;
    se[m] = a1;
  }
  for (int br = 0; br < 2; ++br) {
    const float* v = br ? se : xe;
    const int bbr = br * 4 + b;
    unsigned int rw[16];
#pragma unroll
    for (int q = 0; q < 16; ++q) rw[q] = 0;
#pragma unroll
    for (int k = 0; k < 16; ++k) {
      ushortT h = f2bf(v[k]);
      float hf = bf2f(h);
      ushortT lo = f2bf(v[k] - hf);
      rw[k >> 1] |= ((unsigned int)h) << (16 * (k & 1));
      rw[8 + (k >> 1)] |= ((unsigned int)lo) << (16 * (k & 1));
      tl[k][tid] = h;
    }
    uint4* dst = (uint4*)(Ehl + ((size_t)bbr * NN + n) * 32);
    dst[0] = make_uint4(rw[0], rw[1], rw[2], rw[3]);
    dst[1] = make_uint4(rw[4], rw[5], rw[6], rw[7]);
    dst[2] = make_uint4(rw[8], rw[9], rw[10], rw[11]);
    dst[3] = make_uint4(rw[12], rw[13], rw[14], rw[15]);
    __syncthreads();
    {
      const int r = tid >> 4, c0 = (tid & 15) * 16;
      const uint4* src = (const uint4*)(&tl[r][c0]);
      uint4* d2 = (uint4*)(Et + ((size_t)bbr * 16 + r) * NN + n0 + c0);
      d2[0] = src[0];
      d2[1] = src[1];
    }
    __syncthreads();
  }
}

// ---------------------------------------------------------------- pass A (MFMA)
// lse[n] = log sum_m exp(G[n,m]); G via bf16x3 MFMA; online per-lane reduce.
__global__ __launch_bounds__(TPB) void passA_kernel(
    const ushortT* __restrict__ Ehl, float* __restrict__ lse) {
  const int bbr = blockIdx.z;
  const int n0 = blockIdx.x * 16;
  const int tid = threadIdx.x;
  const int w = tid >> 6, lane = tid & 63;
  const int lr = lane & 15, g = lane >> 4;
  const ushortT* Eb = Ehl + (size_t)bbr * NN * 32;

  // B frags: n-side. B1 = [Eh|Eh], B2 = [El|0]
  const ushortT* rp = Eb + (size_t)(n0 + lr) * 32;
  short8v b1 = *(const short8v*)(rp + (g & 1) * 8);
  short8v b2 = {0, 0, 0, 0, 0, 0, 0, 0};
  if (g < 2) b2 = *(const short8v*)(rp + 16 + g * 8);

  float mx = -INFINITY, sm = 0.f;
  const f32x4 z = {0.f, 0.f, 0.f, 0.f};
  for (int ch = 0; ch < 32; ++ch) {
    const int mb = w * 1024 + ch * 32;
    short8v a0 = *(const short8v*)(Eb + (size_t)(mb + lr) * 32 + g * 8);
    short8v a1 = *(const short8v*)(Eb + (size_t)(mb + 16 + lr) * 32 + g * 8);
    f32x4 c0 = __builtin_amdgcn_mfma_f32_16x16x32_bf16(a0, b1, z, 0, 0, 0);
    c0 = __builtin_amdgcn_mfma_f32_16x16x32_bf16(a0, b2, c0, 0, 0, 0);
    f32x4 c1 = __builtin_amdgcn_mfma_f32_16x16x32_bf16(a1, b1, z, 0, 0, 0);
    c1 = __builtin_amdgcn_mfma_f32_16x16x32_bf16(a1, b2, c1, 0, 0, 0);
    float tmax = fmaxf(fmaxf(fmaxf(c0[0], c0[1]), fmaxf(c0[2], c0[3])),
                       fmaxf(fmaxf(c1[0], c1[1]), fmaxf(c1[2], c1[3])));
    float nm = fmaxf(mx, tmax);
    float ssum = __expf(c0[0] - nm) + __expf(c0[1] - nm) +
                 __expf(c0[2] - nm) + __expf(c0[3] - nm) +
                 __expf(c1[0] - nm) + __expf(c1[1] - nm) +
                 __expf(c1[2] - nm) + __expf(c1[3] - nm);
    sm = fmaf(sm, __expf(mx - nm), ssum);
    mx = nm;
  }
  // merge the 4 lane-groups (same col n, disjoint m subsets)
  for (int off = 16; off < 64; off <<= 1) {
    float omx = __shfl_xor(mx, off);
    float osm = __shfl_xor(sm, off);
    float nm = fmaxf(mx, omx);
    sm = sm * __expf(mx - nm) + osm * __expf(omx - nm);
    mx = nm;
  }
  __shared__ float smx[4][16], ssm[4][16];
  if (lane < 16) { smx[w][lr] = mx; ssm[w][lr] = sm; }
  __syncthreads();
  if (tid < 16) {
    float M = fmaxf(fmaxf(smx[0][tid], smx[1][tid]),
                    fmaxf(smx[2][tid], smx[3][tid]));
    float Ssum = ssm[0][tid] * __expf(smx[0][tid] - M) +
                 ssm[1][tid] * __expf(smx[1][tid] - M) +
                 ssm[2][tid] * __expf(smx[2][tid] - M) +
                 ssm[3][tid] * __expf(smx[3][tid] - M);
    lse[(size_t)bbr * NN + n0 + tid] = M + logf(Ssum);
  }
}

// ---------------------------------------------------------------- pass B (MFMA)
// Ea[l,m] = sum_n exp(G[n,m]-lse[n]) * E[l,n]; G MFMA -> exp -> bf16 P in LDS
// -> PV MFMA. Waves split n; cross-wave reduce at end.
__global__ __launch_bounds__(TPB) void passB_kernel(
    const ushortT* __restrict__ Ehl, const ushortT* __restrict__ Et,
    const float* __restrict__ lse, float* __restrict__ Ea) {
  const int bbr = blockIdx.z;
  const int m0 = blockIdx.x * 16;
  const int tid = threadIdx.x;
  const int w = tid >> 6, lane = tid & 63;
  const int lr = lane & 15, g = lane >> 4;
  const ushortT* Eb = Ehl + (size_t)bbr * NN * 32;
  const ushortT* Tb = Et + (size_t)bbr * 16 * NN;
  __shared__ float lseb[4096];
  __shared__ ushortT pbuf[4][16][40];   // [wave][m][n] stride 80B (2-way max)
  __shared__ float red[4][16][17];
  for (int i = tid; i < 4096; i += TPB) lseb[i] = lse[(size_t)bbr * NN + i];
  __syncthreads();

  // B frags: m-side
  const ushortT* rp = Eb + (size_t)(m0 + lr) * 32;
  short8v b1 = *(const short8v*)(rp + (g & 1) * 8);
  short8v b2 = {0, 0, 0, 0, 0, 0, 0, 0};
  if (g < 2) b2 = *(const short8v*)(rp + 16 + g * 8);

  f32x4 acc = {0.f, 0.f, 0.f, 0.f};
  const f32x4 z = {0.f, 0.f, 0.f, 0.f};
  ushortT* pw = &pbuf[w][0][0];
  for (int ch = 0; ch < 32; ++ch) {
    const int nb = w * 1024 + ch * 32;
    short8v a0 = *(const short8v*)(Eb + (size_t)(nb + lr) * 32 + g * 8);
    short8v a1 = *(const short8v*)(Eb + (size_t)(nb + 16 + lr) * 32 + g * 8);
    f32x4 c0 = __builtin_amdgcn_mfma_f32_16x16x32_bf16(a0, b1, z, 0, 0, 0);
    c0 = __builtin_amdgcn_mfma_f32_16x16x32_bf16(a0, b2, c0, 0, 0, 0);
    f32x4 c1 = __builtin_amdgcn_mfma_f32_16x16x32_bf16(a1, b1, z, 0, 0, 0);
    c1 = __builtin_amdgcn_mfma_f32_16x16x32_bf16(a1, b2, c1, 0, 0, 0);
    const int nr = nb + g * 4;
    float p0 = __expf(c0[0] - lseb[nr + 0]);
    float p1 = __expf(c0[1] - lseb[nr + 1]);
    float p2 = __expf(c0[2] - lseb[nr + 2]);
    float p3 = __expf(c0[3] - lseb[nr + 3]);
    float q0 = __expf(c1[0] - lseb[nr + 16]);
    float q1 = __expf(c1[1] - lseb[nr + 17]);
    float q2 = __expf(c1[2] - lseb[nr + 18]);
    float q3 = __expf(c1[3] - lseb[nr + 19]);
    unsigned int u0, u1, u2, u3;
    asm("v_cvt_pk_bf16_f32 %0, %1, %2" : "=v"(u0) : "v"(p0), "v"(p1));
    asm("v_cvt_pk_bf16_f32 %0, %1, %2" : "=v"(u1) : "v"(p2), "v"(p3));
    asm("v_cvt_pk_bf16_f32 %0, %1, %2" : "=v"(u2) : "v"(q0), "v"(q1));
    asm("v_cvt_pk_bf16_f32 %0, %1, %2" : "=v"(u3) : "v"(q2), "v"(q3));
    *(uint2*)(pw + lr * 40 + g * 4) = make_uint2(u0, u1);
    *(uint2*)(pw + lr * 40 + 16 + g * 4) = make_uint2(u2, u3);
    // per-wave private LDS: DS pipe is in-order, compiler inserts lgkmcnt
    short8v pf = *(const short8v*)(pw + lr * 40 + g * 8);
    short8v ae = *(const short8v*)(Tb + (size_t)lr * NN + nb + g * 8);
    acc = __builtin_amdgcn_mfma_f32_16x16x32_bf16(ae, pf, acc, 0, 0, 0);
  }
#pragma unroll
  for (int r = 0; r < 4; ++r) red[w][g * 4 + r][lr] = acc[r];
  __syncthreads();
  {
    const int l = tid >> 4, m = tid & 15;
    float v = red[0][l][m] + red[1][l][m] + red[2][l][m] + red[3][l][m];
    Ea[((size_t)bbr * NN + m0 + m) * 16 + l] = v;
  }
}

// ---------------------------------------------------------------- M-mix + assemble conv inputs
__global__ __launch_bounds__(TPB) void mmix_kernel(
    const float* __restrict__ Ea,
    const float* __restrict__ W2x, const float* __restrict__ W2s,
    const float* __restrict__ X, const float* __restrict__ S,
    float* __restrict__ Xhat, float* __restrict__ Shat) {
  const int jt = blockIdx.x;   // 0..31
  const int b = blockIdx.y;    // 0..3
  const int br = blockIdx.z;   // 0..1
  const float* W2 = br ? W2s : W2x;
  const float* A = Ea + (size_t)(br * 4 + b) * (NN * LL);
  __shared__ float ldsA[64 * 36];
  __shared__ float ldsW[64 * 64];
  const int tid = threadIdx.x;
  const int r = tid & 31, jq = tid >> 5;
  const int j0 = jt * 64;
  float acc[8];
#pragma unroll
  for (int i = 0; i < 8; ++i) acc[i] = 0.f;

  for (int k0 = 0; k0 < KK; k0 += 64) {
    __syncthreads();
    {
      const float4* src = (const float4*)(A + (size_t)k0 * 32);
#pragma unroll
      for (int q = 0; q < 2; ++q) {
        const int f4 = tid * 2 + q;
        float4 v = src[f4];
        const int kkk = f4 >> 3;
        const int rr = (f4 & 7) * 4;
        *((float4*)(ldsA + kkk * 36 + rr)) = v;
      }
#pragma unroll
      for (int q = 0; q < 4; ++q) {
        const int f4 = q * 256 + tid;
        const int kkk = f4 >> 4;
        const int jj = (f4 & 15) * 4;
        float4 v = *(const float4*)(W2 + (size_t)(k0 + kkk) * KK + j0 + jj);
        *((float4*)(ldsW + kkk * 64 + jj)) = v;
      }
    }
    __syncthreads();
#pragma unroll 4
    for (int kk2 = 0; kk2 < 64; ++kk2) {
      const float a = ldsA[kk2 * 36 + r];
      const float4 w0 = *(const float4*)(ldsW + kk2 * 64 + jq * 8);
      const float4 w1 = *(const float4*)(ldsW + kk2 * 64 + jq * 8 + 4);
      acc[0] = fmaf(a, w0.x, acc[0]);
      acc[1] = fmaf(a, w0.y, acc[1]);
      acc[2] = fmaf(a, w0.z, acc[2]);
      acc[3] = fmaf(a, w0.w, acc[3]);
      acc[4] = fmaf(a, w1.x, acc[4]);
      acc[5] = fmaf(a, w1.y, acc[5]);
      acc[6] = fmaf(a, w1.z, acc[6]);
      acc[7] = fmaf(a, w1.w, acc[7]);
    }
  }
  const int t = r >> 4, l = r & 15;
#pragma unroll
  for (int i = 0; i < 8; ++i) {
    const int j = j0 + jq * 8 + i;
    const int n = j * 2 + t;
    if (br == 0) {
      const float xv = X[(size_t)(b * 16 + l) * NN + n];
      Xhat[((size_t)(b * 32 + l) * KK + j) * 2 + t] = acc[i] * xv;
      Xhat[((size_t)(b * 32 + 16 + l) * KK + j) * 2 + t] = xv;
    } else {
      const float sv = S[(size_t)(b * 16 + l) * NN + n];
      const float pe = t ? cosf((float)j) : sinf((float)j);
      Shat[((size_t)(b * 32 + l) * KK + j) * 2 + t] = fmaf(acc[i], sv, pe);
      Shat[((size_t)(b * 32 + 16 + l) * KK + j) * 2 + t] = sv + pe;
    }
  }
}

// ---------------------------------------------------------------- 3x3 SAME conv, H=2048 W=2
__global__ __launch_bounds__(TPB) void conv_kernel(
    const float* __restrict__ Xhat, const float* __restrict__ Shat,
    const float* __restrict__ Wx, const float* __restrict__ Bx,
    const float* __restrict__ Ws, const float* __restrict__ Bs,
    float* __restrict__ out) {
  const int kt = blockIdx.x;
  const int b = blockIdx.y;
  const int br = blockIdx.z;
  const float* In = (br ? Shat : Xhat) + (size_t)b * 32 * KK * 2;
  const float* Wt = br ? Ws : Wx;
  const float* Bi = br ? Bs : Bx;
  __shared__ float inT[32 * 66 * 2];
  __shared__ float wts[32 * 289];
  const int tid = threadIdx.x;
  const int k0 = kt * 64;

  for (int f = tid; f < 32 * 288; f += TPB) {
    const int c = f / 288, rem = f % 288;
    wts[c * 289 + rem] = Wt[f];
  }
  for (int f = tid; f < 32 * 66 * 2; f += TPB) {
    const int ch = f / 132, rem = f % 132;
    const int kk = rem >> 1, t = rem & 1;
    const int kg = k0 - 1 + kk;
    inT[f] = (kg >= 0 && kg < KK) ? In[((size_t)ch * KK + kg) * 2 + t] : 0.f;
  }
  __syncthreads();

  const int c = tid >> 3, sub = tid & 7;
  const float bias = Bi[c];
  float acc0[8], acc1[8];
#pragma unroll
  for (int i = 0; i < 8; ++i) { acc0[i] = bias; acc1[i] = bias; }

  for (int cin = 0; cin < 32; ++cin) {
    const float* wp = wts + c * 289 + cin * 9;
    const float w00 = wp[0], w01 = wp[1], w02 = wp[2];
    const float w10 = wp[3], w11 = wp[4], w12 = wp[5];
    const float w20 = wp[6], w21 = wp[7], w22 = wp[8];
    const float* ip = inT + cin * 132;
#pragma unroll
    for (int i = 0; i < 8; ++i) {
      const int kl = sub + 8 * i;
      const float* q = ip + kl * 2;
      const float i00 = q[0], i01 = q[1];
      const float i10 = q[2], i11 = q[3];
      const float i20 = q[4], i21 = q[5];
      acc0[i] = fmaf(i00, w01, acc0[i]); acc0[i] = fmaf(i01, w02, acc0[i]);
      acc0[i] = fmaf(i10, w11, acc0[i]); acc0[i] = fmaf(i11, w12, acc0[i]);
      acc0[i] = fmaf(i20, w21, acc0[i]); acc0[i] = fmaf(i21, w22, acc0[i]);
      acc1[i] = fmaf(i00, w00, acc1[i]); acc1[i] = fmaf(i01, w01, acc1[i]);
      acc1[i] = fmaf(i10, w10, acc1[i]); acc1[i] = fmaf(i11, w11, acc1[i]);
      acc1[i] = fmaf(i20, w20, acc1[i]); acc1[i] = fmaf(i21, w21, acc1[i]);
    }
  }
#pragma unroll
  for (int i = 0; i < 8; ++i) {
    const int k = k0 + sub + 8 * i;
    const size_t o = ((size_t)(b * 64 + br * 32 + c) * KK + k) * 2;
    out[o] = acc0[i];
    out[o + 1] = acc1[i];
  }
}

// ---------------------------------------------------------------- launch
extern "C" void kernel_launch(void* const* d_in, const int* in_sizes, int n_in,
                              void* d_out, int out_size, void* d_ws, size_t ws_size,
                              hipStream_t stream) {
  (void)in_sizes; (void)n_in; (void)out_size; (void)ws_size;
  const float* X   = (const float*)d_in[0];
  const float* S   = (const float*)d_in[1];
  const float* W1x = (const float*)d_in[2];
  const float* W1s = (const float*)d_in[3];
  const float* W2x = (const float*)d_in[4];
  const float* W2s = (const float*)d_in[5];
  const float* Cwx = (const float*)d_in[6];
  const float* Cbx = (const float*)d_in[7];
  const float* Cws = (const float*)d_in[8];
  const float* Cbs = (const float*)d_in[9];
  float* out = (float*)d_out;
  float* ws = (float*)d_ws;

  float* Ea = ws + OFF_EA;
  ushortT* Ehl = (ushortT*)(ws + OFF_EHL);
  ushortT* Et = (ushortT*)(ws + OFF_ET);
  float* lse = ws + OFF_LSE;
  float* Xh = ws + OFF_XH;
  float* Sh = ws + OFF_SH;

  hipLaunchKernelGGL(prep_kernel, dim3(16, NBATCH), dim3(TPB), 0, stream,
                     X, S, W1x, W1s, Ehl, Et);
  hipLaunchKernelGGL(passA_kernel, dim3(256, 1, 8), dim3(TPB), 0, stream,
                     Ehl, lse);
  hipLaunchKernelGGL(passB_kernel, dim3(256, 1, 8), dim3(TPB), 0, stream,
                     Ehl, Et, lse, Ea);
  hipLaunchKernelGGL(mmix_kernel, dim3(32, NBATCH, 2), dim3(TPB), 0, stream,
                     Ea, W2x, W2s, X, S, Xh, Sh);
  hipLaunchKernelGGL(conv_kernel, dim3(32, NBATCH, 2), dim3(TPB), 0, stream,
                     Xh, Sh, Cwx, Cbx, Cws, Cbs, out);
}

// Round 3
// 163.825 us; speedup vs baseline: 2.2247x; 1.2632x over previous
//
#include <hip/hip_runtime.h>
#include <math.h>

#define TPB 256

static constexpr int LL = 16;
static constexpr int KK = 2048;
static constexpr int NBATCH = 4;
static constexpr int NN = 4096;        // K*B
static constexpr int BBR = 8;          // (branch, batch) combos

// workspace layout in float slots
static constexpr size_t OFF_EHL = 0;          // 8*4096*32 bf16 = 524288 f
static constexpr size_t OFF_ET  = 524288;     // 8*16*4096 bf16 = 262144 f
static constexpr size_t OFF_LSE = 786432;     // 8*4096 f32 = 32768 f
static constexpr size_t OFF_EAT = 819200;     // 8*2*16*2048 bf16 = 262144 f
static constexpr size_t OFF_XH  = 1081344;    // 4*32*2048*2 f32 = 524288 f
static constexpr size_t OFF_SH  = 1605632;    // 524288 f

typedef unsigned short ushortT;
typedef __attribute__((ext_vector_type(8))) short short8v;
typedef __attribute__((ext_vector_type(4))) float f32x4;

__device__ __forceinline__ ushortT f2bf(float x) {
  union { float f; unsigned int u; } c; c.f = x;
  unsigned int u = c.u;
  return (ushortT)((u + 0x7FFFu + ((u >> 16) & 1u)) >> 16);
}
__device__ __forceinline__ float bf2f(ushortT h) {
  union { unsigned int u; float f; } c; c.u = ((unsigned int)h) << 16;
  return c.f;
}

// ---------------------------------------------------------------- prep
__global__ __launch_bounds__(TPB) void prep_kernel(
    const float* __restrict__ X, const float* __restrict__ S,
    const float* __restrict__ W1x, const float* __restrict__ W1s,
    ushortT* __restrict__ Ehl, ushortT* __restrict__ Et) {
  __shared__ float w1x[256], w1s[256];
  __shared__ ushortT tl[16][272];
  const int tid = threadIdx.x;
  w1x[tid] = W1x[tid];
  w1s[tid] = W1s[tid];
  __syncthreads();
  const int n0 = blockIdx.x * 256;
  const int b = blockIdx.y;
  const int n = n0 + tid;
  float s[16], x[16];
#pragma unroll
  for (int l = 0; l < 16; ++l) {
    s[l] = S[(size_t)(b * 16 + l) * NN + n];
    x[l] = X[(size_t)(b * 16 + l) * NN + n];
  }
  float xe[16], se[16];
#pragma unroll
  for (int m = 0; m < 16; ++m) {
    float a0 = 0.f, a1 = 0.f;
#pragma unroll
    for (int l = 0; l < 16; ++l) {
      a0 = fmaf(s[l], w1x[l * 16 + m], a0);
      a1 = fmaf(x[l], w1s[l * 16 + m], a1);
    }
    xe[m] = a0;
    se[m] = a1;
  }
  for (int br = 0; br < 2; ++br) {
    const float* v = br ? se : xe;
    const int bbr = br * 4 + b;
    unsigned int rw[16];
#pragma unroll
    for (int q = 0; q < 16; ++q) rw[q] = 0;
#pragma unroll
    for (int k = 0; k < 16; ++k) {
      ushortT h = f2bf(v[k]);
      float hf = bf2f(h);
      ushortT lo = f2bf(v[k] - hf);
      rw[k >> 1] |= ((unsigned int)h) << (16 * (k & 1));
      rw[8 + (k >> 1)] |= ((unsigned int)lo) << (16 * (k & 1));
      tl[k][tid] = h;
    }
    uint4* dst = (uint4*)(Ehl + ((size_t)bbr * NN + n) * 32);
    dst[0] = make_uint4(rw[0], rw[1], rw[2], rw[3]);
    dst[1] = make_uint4(rw[4], rw[5], rw[6], rw[7]);
    dst[2] = make_uint4(rw[8], rw[9], rw[10], rw[11]);
    dst[3] = make_uint4(rw[12], rw[13], rw[14], rw[15]);
    __syncthreads();
    {
      const int r = tid >> 4, c0 = (tid & 15) * 16;
      const uint4* src = (const uint4*)(&tl[r][c0]);
      uint4* d2 = (uint4*)(Et + ((size_t)bbr * 16 + r) * NN + n0 + c0);
      d2[0] = src[0];
      d2[1] = src[1];
    }
    __syncthreads();
  }
}

// ---------------------------------------------------------------- pass A (MFMA)
__global__ __launch_bounds__(TPB) void passA_kernel(
    const ushortT* __restrict__ Ehl, float* __restrict__ lse) {
  const int bbr = blockIdx.z;
  const int n0 = blockIdx.x * 16;
  const int tid = threadIdx.x;
  const int w = tid >> 6, lane = tid & 63;
  const int lr = lane & 15, g = lane >> 4;
  const ushortT* Eb = Ehl + (size_t)bbr * NN * 32;

  const ushortT* rp = Eb + (size_t)(n0 + lr) * 32;
  short8v b1 = *(const short8v*)(rp + (g & 1) * 8);
  short8v b2 = {0, 0, 0, 0, 0, 0, 0, 0};
  if (g < 2) b2 = *(const short8v*)(rp + 16 + g * 8);

  float mx = -INFINITY, sm = 0.f;
  const f32x4 z = {0.f, 0.f, 0.f, 0.f};
  for (int ch = 0; ch < 32; ++ch) {
    const int mb = w * 1024 + ch * 32;
    short8v a0 = *(const short8v*)(Eb + (size_t)(mb + lr) * 32 + g * 8);
    short8v a1 = *(const short8v*)(Eb + (size_t)(mb + 16 + lr) * 32 + g * 8);
    f32x4 c0 = __builtin_amdgcn_mfma_f32_16x16x32_bf16(a0, b1, z, 0, 0, 0);
    c0 = __builtin_amdgcn_mfma_f32_16x16x32_bf16(a0, b2, c0, 0, 0, 0);
    f32x4 c1 = __builtin_amdgcn_mfma_f32_16x16x32_bf16(a1, b1, z, 0, 0, 0);
    c1 = __builtin_amdgcn_mfma_f32_16x16x32_bf16(a1, b2, c1, 0, 0, 0);
    float tmax = fmaxf(fmaxf(fmaxf(c0[0], c0[1]), fmaxf(c0[2], c0[3])),
                       fmaxf(fmaxf(c1[0], c1[1]), fmaxf(c1[2], c1[3])));
    float nm = fmaxf(mx, tmax);
    float ssum = __expf(c0[0] - nm) + __expf(c0[1] - nm) +
                 __expf(c0[2] - nm) + __expf(c0[3] - nm) +
                 __expf(c1[0] - nm) + __expf(c1[1] - nm) +
                 __expf(c1[2] - nm) + __expf(c1[3] - nm);
    sm = fmaf(sm, __expf(mx - nm), ssum);
    mx = nm;
  }
  for (int off = 16; off < 64; off <<= 1) {
    float omx = __shfl_xor(mx, off);
    float osm = __shfl_xor(sm, off);
    float nm = fmaxf(mx, omx);
    sm = sm * __expf(mx - nm) + osm * __expf(omx - nm);
    mx = nm;
  }
  __shared__ float smx[4][16], ssm[4][16];
  if (lane < 16) { smx[w][lr] = mx; ssm[w][lr] = sm; }
  __syncthreads();
  if (tid < 16) {
    float M = fmaxf(fmaxf(smx[0][tid], smx[1][tid]),
                    fmaxf(smx[2][tid], smx[3][tid]));
    float Ssum = ssm[0][tid] * __expf(smx[0][tid] - M) +
                 ssm[1][tid] * __expf(smx[1][tid] - M) +
                 ssm[2][tid] * __expf(smx[2][tid] - M) +
                 ssm[3][tid] * __expf(smx[3][tid] - M);
    lse[(size_t)bbr * NN + n0 + tid] = M + logf(Ssum);
  }
}

// ---------------------------------------------------------------- pass B (MFMA)
// Ea[l,m] = sum_n exp(G[n,m]-lse[n]) * E[l,n]; output to EaT bf16 [bbr][t][l][k]
__global__ __launch_bounds__(TPB) void passB_kernel(
    const ushortT* __restrict__ Ehl, const ushortT* __restrict__ Et,
    const float* __restrict__ lse, ushortT* __restrict__ EaT) {
  const int bbr = blockIdx.z;
  const int m0 = blockIdx.x * 16;
  const int tid = threadIdx.x;
  const int w = tid >> 6, lane = tid & 63;
  const int lr = lane & 15, g = lane >> 4;
  const ushortT* Eb = Ehl + (size_t)bbr * NN * 32;
  const ushortT* Tb = Et + (size_t)bbr * 16 * NN;
  __shared__ float lseb[4096];
  __shared__ ushortT pbuf[4][16][40];
  __shared__ float red[4][16][17];
  for (int i = tid; i < 4096; i += TPB) lseb[i] = lse[(size_t)bbr * NN + i];
  __syncthreads();

  const ushortT* rp = Eb + (size_t)(m0 + lr) * 32;
  short8v b1 = *(const short8v*)(rp + (g & 1) * 8);
  short8v b2 = {0, 0, 0, 0, 0, 0, 0, 0};
  if (g < 2) b2 = *(const short8v*)(rp + 16 + g * 8);

  f32x4 acc = {0.f, 0.f, 0.f, 0.f};
  const f32x4 z = {0.f, 0.f, 0.f, 0.f};
  ushortT* pw = &pbuf[w][0][0];
  for (int ch = 0; ch < 32; ++ch) {
    const int nb = w * 1024 + ch * 32;
    short8v a0 = *(const short8v*)(Eb + (size_t)(nb + lr) * 32 + g * 8);
    short8v a1 = *(const short8v*)(Eb + (size_t)(nb + 16 + lr) * 32 + g * 8);
    f32x4 c0 = __builtin_amdgcn_mfma_f32_16x16x32_bf16(a0, b1, z, 0, 0, 0);
    c0 = __builtin_amdgcn_mfma_f32_16x16x32_bf16(a0, b2, c0, 0, 0, 0);
    f32x4 c1 = __builtin_amdgcn_mfma_f32_16x16x32_bf16(a1, b1, z, 0, 0, 0);
    c1 = __builtin_amdgcn_mfma_f32_16x16x32_bf16(a1, b2, c1, 0, 0, 0);
    const int nr = nb + g * 4;
    float p0 = __expf(c0[0] - lseb[nr + 0]);
    float p1 = __expf(c0[1] - lseb[nr + 1]);
    float p2 = __expf(c0[2] - lseb[nr + 2]);
    float p3 = __expf(c0[3] - lseb[nr + 3]);
    float q0 = __expf(c1[0] - lseb[nr + 16]);
    float q1 = __expf(c1[1] - lseb[nr + 17]);
    float q2 = __expf(c1[2] - lseb[nr + 18]);
    float q3 = __expf(c1[3] - lseb[nr + 19]);
    unsigned int u0, u1, u2, u3;
    asm("v_cvt_pk_bf16_f32 %0, %1, %2" : "=v"(u0) : "v"(p0), "v"(p1));
    asm("v_cvt_pk_bf16_f32 %0, %1, %2" : "=v"(u1) : "v"(p2), "v"(p3));
    asm("v_cvt_pk_bf16_f32 %0, %1, %2" : "=v"(u2) : "v"(q0), "v"(q1));
    asm("v_cvt_pk_bf16_f32 %0, %1, %2" : "=v"(u3) : "v"(q2), "v"(q3));
    *(uint2*)(pw + lr * 40 + g * 4) = make_uint2(u0, u1);
    *(uint2*)(pw + lr * 40 + 16 + g * 4) = make_uint2(u2, u3);
    short8v pf = *(const short8v*)(pw + lr * 40 + g * 8);
    short8v ae = *(const short8v*)(Tb + (size_t)lr * NN + nb + g * 8);
    acc = __builtin_amdgcn_mfma_f32_16x16x32_bf16(ae, pf, acc, 0, 0, 0);
  }
#pragma unroll
  for (int r = 0; r < 4; ++r) red[w][g * 4 + r][lr] = acc[r];
  __syncthreads();
  {
    const int l = tid >> 4, m = tid & 15;
    float v = red[0][l][m] + red[1][l][m] + red[2][l][m] + red[3][l][m];
    const int M = m0 + m;
    EaT[((size_t)(bbr * 2 + (M & 1)) * 16 + l) * (size_t)KK + (M >> 1)] = f2bf(v);
  }
}

// ---------------------------------------------------------------- M-mix (MFMA) + assemble conv inputs
// M[(b,l,t), j] = sum_k EaT[bbr][t][l][k] * W2[k, j]; W2 f32 staged->bf16 LDS.
__global__ __launch_bounds__(TPB) void mmix_kernel(
    const ushortT* __restrict__ EaT,
    const float* __restrict__ W2x, const float* __restrict__ W2s,
    const float* __restrict__ X, const float* __restrict__ S,
    float* __restrict__ Xhat, float* __restrict__ Shat) {
  const int jt = blockIdx.x;   // 0..127
  const int br = blockIdx.y;   // 0..1
  const float* W2 = br ? W2s : W2x;
  const int j0 = jt * 16;
  const int tid = threadIdx.x;
  const int w = tid >> 6, lane = tid & 63;
  const int b = w;
  const int lj = tid & 15, kp0 = tid >> 4;   // staging map: j=lj, word kp0 & kp0+16
  const int fl = lane & 15, g = lane >> 4;
  __shared__ ushortT bpan[2][16][72];        // [buf][j][k] rows 144B (16B aligned)

  const size_t rb0 = ((size_t)(br * 4 + b) * 2 + 0) * 16;  // t=0 row base (l adds)
  const size_t rb1 = ((size_t)(br * 4 + b) * 2 + 1) * 16;  // t=1

  f32x4 acc0 = {0.f, 0.f, 0.f, 0.f};
  f32x4 acc1 = {0.f, 0.f, 0.f, 0.f};

  float r0, r1, r2, r3;
  r0 = W2[(size_t)(2 * kp0)      * KK + j0 + lj];
  r1 = W2[(size_t)(2 * kp0 + 1)  * KK + j0 + lj];
  r2 = W2[(size_t)(2 * kp0 + 32) * KK + j0 + lj];
  r3 = W2[(size_t)(2 * kp0 + 33) * KK + j0 + lj];

  for (int c = 0; c < 32; ++c) {
    const int cur = c & 1;
    unsigned int u0, u1;
    asm("v_cvt_pk_bf16_f32 %0, %1, %2" : "=v"(u0) : "v"(r0), "v"(r1));
    asm("v_cvt_pk_bf16_f32 %0, %1, %2" : "=v"(u1) : "v"(r2), "v"(r3));
    *(unsigned int*)(&bpan[cur][lj][kp0 * 2]) = u0;
    *(unsigned int*)(&bpan[cur][lj][(kp0 + 16) * 2]) = u1;
    __syncthreads();
    if (c < 31) {
      const int kc = (c + 1) * 64;
      r0 = W2[(size_t)(kc + 2 * kp0)      * KK + j0 + lj];
      r1 = W2[(size_t)(kc + 2 * kp0 + 1)  * KK + j0 + lj];
      r2 = W2[(size_t)(kc + 2 * kp0 + 32) * KK + j0 + lj];
      r3 = W2[(size_t)(kc + 2 * kp0 + 33) * KK + j0 + lj];
    }
#pragma unroll
    for (int s = 0; s < 2; ++s) {
      const int k = c * 64 + s * 32 + g * 8;
      short8v bf = *(const short8v*)(&bpan[cur][fl][s * 32 + g * 8]);
      short8v a0 = *(const short8v*)(EaT + (rb0 + fl) * (size_t)KK + k);
      short8v a1 = *(const short8v*)(EaT + (rb1 + fl) * (size_t)KK + k);
      acc0 = __builtin_amdgcn_mfma_f32_16x16x32_bf16(a0, bf, acc0, 0, 0, 0);
      acc1 = __builtin_amdgcn_mfma_f32_16x16x32_bf16(a1, bf, acc1, 0, 0, 0);
    }
    __syncthreads();
  }

  // epilogue: C row = l = g*4+r, col = j = j0+fl
  const int j = j0 + fl;
#pragma unroll
  for (int r = 0; r < 4; ++r) {
    const int l = g * 4 + r;
    if (br == 0) {
      // t=0
      float xv0 = X[(size_t)(b * 16 + l) * NN + 2 * j + 0];
      Xhat[((size_t)(b * 32 + l) * KK + j) * 2 + 0] = acc0[r] * xv0;
      Xhat[((size_t)(b * 32 + 16 + l) * KK + j) * 2 + 0] = xv0;
      // t=1
      float xv1 = X[(size_t)(b * 16 + l) * NN + 2 * j + 1];
      Xhat[((size_t)(b * 32 + l) * KK + j) * 2 + 1] = acc1[r] * xv1;
      Xhat[((size_t)(b * 32 + 16 + l) * KK + j) * 2 + 1] = xv1;
    } else {
      float pe0 = sinf((float)j), pe1 = cosf((float)j);
      float sv0 = S[(size_t)(b * 16 + l) * NN + 2 * j + 0];
      Shat[((size_t)(b * 32 + l) * KK + j) * 2 + 0] = fmaf(acc0[r], sv0, pe0);
      Shat[((size_t)(b * 32 + 16 + l) * KK + j) * 2 + 0] = sv0 + pe0;
      float sv1 = S[(size_t)(b * 16 + l) * NN + 2 * j + 1];
      Shat[((size_t)(b * 32 + l) * KK + j) * 2 + 1] = fmaf(acc1[r], sv1, pe1);
      Shat[((size_t)(b * 32 + 16 + l) * KK + j) * 2 + 1] = sv1 + pe1;
    }
  }
}

// ---------------------------------------------------------------- 3x3 SAME conv, H=2048 W=2
__global__ __launch_bounds__(TPB) void conv_kernel(
    const float* __restrict__ Xhat, const float* __restrict__ Shat,
    const float* __restrict__ Wx, const float* __restrict__ Bx,
    const float* __restrict__ Ws, const float* __restrict__ Bs,
    float* __restrict__ out) {
  const int kt = blockIdx.x;
  const int b = blockIdx.y;
  const int br = blockIdx.z;
  const float* In = (br ? Shat : Xhat) + (size_t)b * 32 * KK * 2;
  const float* Wt = br ? Ws : Wx;
  const float* Bi = br ? Bs : Bx;
  __shared__ float inT[32 * 66 * 2];
  __shared__ float wts[32 * 289];
  const int tid = threadIdx.x;
  const int k0 = kt * 64;

  for (int f = tid; f < 32 * 288; f += TPB) {
    const int c = f / 288, rem = f % 288;
    wts[c * 289 + rem] = Wt[f];
  }
  for (int f = tid; f < 32 * 66 * 2; f += TPB) {
    const int ch = f / 132, rem = f % 132;
    const int kk = rem >> 1, t = rem & 1;
    const int kg = k0 - 1 + kk;
    inT[f] = (kg >= 0 && kg < KK) ? In[((size_t)ch * KK + kg) * 2 + t] : 0.f;
  }
  __syncthreads();

  const int c = tid >> 3, sub = tid & 7;
  const float bias = Bi[c];
  float acc0[8], acc1[8];
#pragma unroll
  for (int i = 0; i < 8; ++i) { acc0[i] = bias; acc1[i] = bias; }

  for (int cin = 0; cin < 32; ++cin) {
    const float* wp = wts + c * 289 + cin * 9;
    const float w00 = wp[0], w01 = wp[1], w02 = wp[2];
    const float w10 = wp[3], w11 = wp[4], w12 = wp[5];
    const float w20 = wp[6], w21 = wp[7], w22 = wp[8];
    const float* ip = inT + cin * 132;
#pragma unroll
    for (int i = 0; i < 8; ++i) {
      const int kl = sub + 8 * i;
      const float* q = ip + kl * 2;
      const float i00 = q[0], i01 = q[1];
      const float i10 = q[2], i11 = q[3];
      const float i20 = q[4], i21 = q[5];
      acc0[i] = fmaf(i00, w01, acc0[i]); acc0[i] = fmaf(i01, w02, acc0[i]);
      acc0[i] = fmaf(i10, w11, acc0[i]); acc0[i] = fmaf(i11, w12, acc0[i]);
      acc0[i] = fmaf(i20, w21, acc0[i]); acc0[i] = fmaf(i21, w22, acc0[i]);
      acc1[i] = fmaf(i00, w00, acc1[i]); acc1[i] = fmaf(i01, w01, acc1[i]);
      acc1[i] = fmaf(i10, w10, acc1[i]); acc1[i] = fmaf(i11, w11, acc1[i]);
      acc1[i] = fmaf(i20, w20, acc1[i]); acc1[i] = fmaf(i21, w21, acc1[i]);
    }
  }
#pragma unroll
  for (int i = 0; i < 8; ++i) {
    const int k = k0 + sub + 8 * i;
    const size_t o = ((size_t)(b * 64 + br * 32 + c) * KK + k) * 2;
    out[o] = acc0[i];
    out[o + 1] = acc1[i];
  }
}

// ---------------------------------------------------------------- launch
extern "C" void kernel_launch(void* const* d_in, const int* in_sizes, int n_in,
                              void* d_out, int out_size, void* d_ws, size_t ws_size,
                              hipStream_t stream) {
  (void)in_sizes; (void)n_in; (void)out_size; (void)ws_size;
  const float* X   = (const float*)d_in[0];
  const float* S   = (const float*)d_in[1];
  const float* W1x = (const float*)d_in[2];
  const float* W1s = (const float*)d_in[3];
  const float* W2x = (const float*)d_in[4];
  const float* W2s = (const float*)d_in[5];
  const float* Cwx = (const float*)d_in[6];
  const float* Cbx = (const float*)d_in[7];
  const float* Cws = (const float*)d_in[8];
  const float* Cbs = (const float*)d_in[9];
  float* out = (float*)d_out;
  float* ws = (float*)d_ws;

  ushortT* Ehl = (ushortT*)(ws + OFF_EHL);
  ushortT* Et  = (ushortT*)(ws + OFF_ET);
  float*   lse = ws + OFF_LSE;
  ushortT* EaT = (ushortT*)(ws + OFF_EAT);
  float*   Xh  = ws + OFF_XH;
  float*   Sh  = ws + OFF_SH;

  hipLaunchKernelGGL(prep_kernel, dim3(16, NBATCH), dim3(TPB), 0, stream,
                     X, S, W1x, W1s, Ehl, Et);
  hipLaunchKernelGGL(passA_kernel, dim3(256, 1, 8), dim3(TPB), 0, stream,
                     Ehl, lse);
  hipLaunchKernelGGL(passB_kernel, dim3(256, 1, 8), dim3(TPB), 0, stream,
                     Ehl, Et, lse, EaT);
  hipLaunchKernelGGL(mmix_kernel, dim3(128, 2), dim3(TPB), 0, stream,
                     EaT, W2x, W2s, X, S, Xh, Sh);
  hipLaunchKernelGGL(conv_kernel, dim3(32, NBATCH, 2), dim3(TPB), 0, stream,
                     Xh, Sh, Cwx, Cbx, Cws, Cbs, out);
}

// Round 4
// 134.749 us; speedup vs baseline: 2.7047x; 1.2158x over previous
//
#include <hip/hip_runtime.h>
#include <math.h>

#define TPB 256

static constexpr int LL = 16;
static constexpr int KK = 2048;
static constexpr int NBATCH = 4;
static constexpr int NN = 4096;        // K*B
static constexpr int BBR = 8;          // (branch, batch) combos

// workspace layout in float slots
static constexpr size_t OFF_EHL = 0;          // 8*4096*32 bf16 = 524288 f
static constexpr size_t OFF_ET  = 524288;     // 8*16*4096 bf16 = 262144 f (n-permuted)
static constexpr size_t OFF_LSE = 786432;     // 8*4096 f32 = 32768 f (base-2)
static constexpr size_t OFF_EAT = 819200;     // 8*2*16*2048 bf16 = 262144 f
static constexpr size_t OFF_XH  = 1081344;    // 4*32*2048*2 f32 = 524288 f
static constexpr size_t OFF_SH  = 1605632;    // 524288 f

typedef unsigned short ushortT;
typedef __attribute__((ext_vector_type(8))) short short8v;
typedef __attribute__((ext_vector_type(4))) float f32x4;

__device__ __forceinline__ ushortT f2bf(float x) {
  union { float f; unsigned int u; } c; c.f = x;
  unsigned int u = c.u;
  return (ushortT)((u + 0x7FFFu + ((u >> 16) & 1u)) >> 16);
}
__device__ __forceinline__ float bf2f(ushortT h) {
  union { unsigned int u; float f; } c; c.u = ((unsigned int)h) << 16;
  return c.f;
}
__device__ __forceinline__ float exp2a(float x) {
  float r; asm("v_exp_f32 %0, %1" : "=v"(r) : "v"(x)); return r;
}

// ---------------------------------------------------------------- prep
// E = einsum over L. Ehl[bbr][n][32] = bf16 split of E*sqrt(log2 e): [hi|lo].
// Ept[bbr][l][n] = bf16(E) with n PERMUTED per 32-block so PV B-frags come
// straight from the G-MFMA output registers (slot g*8+j <- sigma(g,j)).
__global__ __launch_bounds__(TPB) void prep_kernel(
    const float* __restrict__ X, const float* __restrict__ S,
    const float* __restrict__ W1x, const float* __restrict__ W1s,
    ushortT* __restrict__ Ehl, ushortT* __restrict__ Ept) {
  __shared__ float w1x[256], w1s[256];
  __shared__ ushortT tl[16][272];
  const int tid = threadIdx.x;
  w1x[tid] = W1x[tid];
  w1s[tid] = W1s[tid];
  __syncthreads();
  const int n0 = blockIdx.x * 256;
  const int b = blockIdx.y;
  const int n = n0 + tid;
  const float SC = 1.2011224087f;  // sqrt(log2(e))
  // permuted column within this 256-block
  const int wq = tid & 31;
  const int slot = (wq < 16) ? ((wq >> 2) * 8 + (wq & 3))
                             : (((wq - 16) >> 2) * 8 + 4 + (wq & 3));
  const int ptid = (tid & ~31) | slot;

  float s[16], x[16];
#pragma unroll
  for (int l = 0; l < 16; ++l) {
    s[l] = S[(size_t)(b * 16 + l) * NN + n];
    x[l] = X[(size_t)(b * 16 + l) * NN + n];
  }
  float xe[16], se[16];
#pragma unroll
  for (int m = 0; m < 16; ++m) {
    float a0 = 0.f, a1 = 0.f;
#pragma unroll
    for (int l = 0; l < 16; ++l) {
      a0 = fmaf(s[l], w1x[l * 16 + m], a0);
      a1 = fmaf(x[l], w1s[l * 16 + m], a1);
    }
    xe[m] = a0;
    se[m] = a1;
  }
  for (int br = 0; br < 2; ++br) {
    const float* v = br ? se : xe;
    const int bbr = br * 4 + b;
    unsigned int rw[16];
#pragma unroll
    for (int q = 0; q < 16; ++q) rw[q] = 0;
#pragma unroll
    for (int k = 0; k < 16; ++k) {
      const float vs = v[k] * SC;
      ushortT h = f2bf(vs);
      ushortT lo = f2bf(vs - bf2f(h));
      rw[k >> 1] |= ((unsigned int)h) << (16 * (k & 1));
      rw[8 + (k >> 1)] |= ((unsigned int)lo) << (16 * (k & 1));
      tl[k][ptid] = f2bf(v[k]);           // unscaled hi for PV operand
    }
    uint4* dst = (uint4*)(Ehl + ((size_t)bbr * NN + n) * 32);
    dst[0] = make_uint4(rw[0], rw[1], rw[2], rw[3]);
    dst[1] = make_uint4(rw[4], rw[5], rw[6], rw[7]);
    dst[2] = make_uint4(rw[8], rw[9], rw[10], rw[11]);
    dst[3] = make_uint4(rw[12], rw[13], rw[14], rw[15]);
    __syncthreads();
    {
      const int r = tid >> 4, c0 = (tid & 15) * 16;
      const uint4* src = (const uint4*)(&tl[r][c0]);
      uint4* d2 = (uint4*)(Ept + ((size_t)bbr * 16 + r) * NN + n0 + c0);
      d2[0] = src[0];
      d2[1] = src[1];
    }
    __syncthreads();
  }
}

// ---------------------------------------------------------------- pass A (MFMA, base-2, defer-max)
// lse2[n] = log2 sum_m 2^(G'[n,m]); 32-n tile per block; bbr = bid%8 (XCD-local).
__global__ __launch_bounds__(TPB) void passA_kernel(
    const ushortT* __restrict__ Ehl, float* __restrict__ lse2) {
  const int bid = blockIdx.x;
  const int bbr = bid & 7;
  const int n0 = (bid >> 3) * 32;
  const int tid = threadIdx.x;
  const int w = tid >> 6, lane = tid & 63;
  const int lr = lane & 15, g = lane >> 4;
  const ushortT* Eb = Ehl + (size_t)bbr * NN * 32;

  const short8v zero8 = {0, 0, 0, 0, 0, 0, 0, 0};
  short8v b1[2], b2[2];
#pragma unroll
  for (int s = 0; s < 2; ++s) {
    const ushortT* rp = Eb + (size_t)(n0 + s * 16 + lr) * 32;
    b1[s] = *(const short8v*)(rp + (g & 1) * 8);
    b2[s] = zero8;
    if (g < 2) b2[s] = *(const short8v*)(rp + 16 + g * 8);
  }
  float mx[2] = {-INFINITY, -INFINITY};
  float sm[2] = {0.f, 0.f};
  const f32x4 z = {0.f, 0.f, 0.f, 0.f};
  const ushortT* ap = Eb + (size_t)(w * 1024 + lr) * 32 + g * 8;
#pragma unroll 2
  for (int ch = 0; ch < 32; ++ch) {
    short8v a0 = *(const short8v*)ap;
    short8v a1 = *(const short8v*)(ap + 16 * 32);
    ap += 32 * 32;
#pragma unroll
    for (int s = 0; s < 2; ++s) {
      f32x4 c0 = __builtin_amdgcn_mfma_f32_16x16x32_bf16(a0, b1[s], z, 0, 0, 0);
      c0 = __builtin_amdgcn_mfma_f32_16x16x32_bf16(a0, b2[s], c0, 0, 0, 0);
      f32x4 c1 = __builtin_amdgcn_mfma_f32_16x16x32_bf16(a1, b1[s], z, 0, 0, 0);
      c1 = __builtin_amdgcn_mfma_f32_16x16x32_bf16(a1, b2[s], c1, 0, 0, 0);
      float t0 = fmaxf(fmaxf(c0[0], c0[1]), fmaxf(c0[2], c0[3]));
      float t1 = fmaxf(fmaxf(c1[0], c1[1]), fmaxf(c1[2], c1[3]));
      float tm = fmaxf(t0, t1);
      if (tm > mx[s] + 30.f) {            // deferred rescale (rare)
        sm[s] *= exp2a(mx[s] - tm);
        mx[s] = tm;
      }
      float e0 = exp2a(c0[0] - mx[s]), e1 = exp2a(c0[1] - mx[s]);
      float e2 = exp2a(c0[2] - mx[s]), e3 = exp2a(c0[3] - mx[s]);
      float e4 = exp2a(c1[0] - mx[s]), e5 = exp2a(c1[1] - mx[s]);
      float e6 = exp2a(c1[2] - mx[s]), e7 = exp2a(c1[3] - mx[s]);
      sm[s] += ((e0 + e1) + (e2 + e3)) + ((e4 + e5) + (e6 + e7));
    }
  }
  // merge the 4 lane-groups (disjoint m subsets, same col n)
#pragma unroll
  for (int s = 0; s < 2; ++s) {
    for (int off = 16; off < 64; off <<= 1) {
      float omx = __shfl_xor(mx[s], off);
      float osm = __shfl_xor(sm[s], off);
      float nm = fmaxf(mx[s], omx);
      sm[s] = sm[s] * exp2a(mx[s] - nm) + osm * exp2a(omx - nm);
      mx[s] = nm;
    }
  }
  __shared__ float smx[4][2][16], ssm[4][2][16];
  if (lane < 16) {
    smx[w][0][lr] = mx[0]; ssm[w][0][lr] = sm[0];
    smx[w][1][lr] = mx[1]; ssm[w][1][lr] = sm[1];
  }
  __syncthreads();
  if (tid < 32) {
    const int s = tid >> 4, col = tid & 15;
    float M = fmaxf(fmaxf(smx[0][s][col], smx[1][s][col]),
                    fmaxf(smx[2][s][col], smx[3][s][col]));
    float Ssum = ssm[0][s][col] * exp2a(smx[0][s][col] - M) +
                 ssm[1][s][col] * exp2a(smx[1][s][col] - M) +
                 ssm[2][s][col] * exp2a(smx[2][s][col] - M) +
                 ssm[3][s][col] * exp2a(smx[3][s][col] - M);
    lse2[(size_t)bbr * NN + n0 + s * 16 + col] = M + log2f(Ssum);
  }
}

// ---------------------------------------------------------------- pass B (MFMA, register-only P)
// Ea[l,m] = sum_n 2^(G'[n,m]-lse2[n]) * E[l,n]; P goes cvt_pk -> PV B-frag
// directly (Ept's n-permutation matches the G C-layout). No LDS P buffer.
__global__ __launch_bounds__(TPB) void passB_kernel(
    const ushortT* __restrict__ Ehl, const ushortT* __restrict__ Ept,
    const float* __restrict__ lse2, ushortT* __restrict__ EaT) {
  const int bid = blockIdx.x;
  const int bbr = bid & 7;
  const int m0 = (bid >> 3) * 32;
  const int tid = threadIdx.x;
  const int w = tid >> 6, lane = tid & 63;
  const int lr = lane & 15, g = lane >> 4;
  const ushortT* Eb = Ehl + (size_t)bbr * NN * 32;
  const ushortT* Tb = Ept + (size_t)bbr * 16 * NN;
  __shared__ float lseb[4096];
  __shared__ float red[4][2][16][17];
  for (int i = tid; i < 4096; i += TPB) lseb[i] = lse2[(size_t)bbr * NN + i];
  __syncthreads();

  const short8v zero8 = {0, 0, 0, 0, 0, 0, 0, 0};
  short8v b1[2], b2[2];
#pragma unroll
  for (int s = 0; s < 2; ++s) {
    const ushortT* rp = Eb + (size_t)(m0 + s * 16 + lr) * 32;
    b1[s] = *(const short8v*)(rp + (g & 1) * 8);
    b2[s] = zero8;
    if (g < 2) b2[s] = *(const short8v*)(rp + 16 + g * 8);
  }
  f32x4 acc[2] = {{0.f, 0.f, 0.f, 0.f}, {0.f, 0.f, 0.f, 0.f}};
  const f32x4 z = {0.f, 0.f, 0.f, 0.f};
  const ushortT* ap = Eb + (size_t)(w * 1024 + lr) * 32 + g * 8;
  const ushortT* vp = Tb + (size_t)lr * NN + w * 1024 + g * 8;
  const float* lp = lseb + w * 1024 + g * 4;
#pragma unroll 2
  for (int ch = 0; ch < 32; ++ch) {
    short8v a0 = *(const short8v*)ap;
    short8v a1 = *(const short8v*)(ap + 16 * 32);
    short8v ae = *(const short8v*)vp;
    float4 l0 = *(const float4*)lp;
    float4 l1 = *(const float4*)(lp + 16);
    ap += 32 * 32; vp += 32; lp += 32;
#pragma unroll
    for (int s = 0; s < 2; ++s) {
      f32x4 c0 = __builtin_amdgcn_mfma_f32_16x16x32_bf16(a0, b1[s], z, 0, 0, 0);
      c0 = __builtin_amdgcn_mfma_f32_16x16x32_bf16(a0, b2[s], c0, 0, 0, 0);
      f32x4 c1 = __builtin_amdgcn_mfma_f32_16x16x32_bf16(a1, b1[s], z, 0, 0, 0);
      c1 = __builtin_amdgcn_mfma_f32_16x16x32_bf16(a1, b2[s], c1, 0, 0, 0);
      float p0 = exp2a(c0[0] - l0.x), p1 = exp2a(c0[1] - l0.y);
      float p2 = exp2a(c0[2] - l0.z), p3 = exp2a(c0[3] - l0.w);
      float q0 = exp2a(c1[0] - l1.x), q1 = exp2a(c1[1] - l1.y);
      float q2 = exp2a(c1[2] - l1.z), q3 = exp2a(c1[3] - l1.w);
      union { unsigned int u[4]; short8v v; } pk;
      asm("v_cvt_pk_bf16_f32 %0, %1, %2" : "=v"(pk.u[0]) : "v"(p0), "v"(p1));
      asm("v_cvt_pk_bf16_f32 %0, %1, %2" : "=v"(pk.u[1]) : "v"(p2), "v"(p3));
      asm("v_cvt_pk_bf16_f32 %0, %1, %2" : "=v"(pk.u[2]) : "v"(q0), "v"(q1));
      asm("v_cvt_pk_bf16_f32 %0, %1, %2" : "=v"(pk.u[3]) : "v"(q2), "v"(q3));
      acc[s] = __builtin_amdgcn_mfma_f32_16x16x32_bf16(ae, pk.v, acc[s], 0, 0, 0);
    }
  }
#pragma unroll
  for (int s = 0; s < 2; ++s)
#pragma unroll
    for (int r = 0; r < 4; ++r) red[w][s][g * 4 + r][lr] = acc[s][r];
  __syncthreads();
  for (int o = tid; o < 512; o += TPB) {
    const int s = o >> 8, rem = o & 255;
    const int l = rem >> 4, mm = rem & 15;
    float v = red[0][s][l][mm] + red[1][s][l][mm] +
              red[2][s][l][mm] + red[3][s][l][mm];
    const int M = m0 + s * 16 + mm;
    EaT[((size_t)(bbr * 2 + (M & 1)) * 16 + l) * (size_t)KK + (M >> 1)] = f2bf(v);
  }
}

// ---------------------------------------------------------------- M-mix (MFMA) + assemble conv inputs
__global__ __launch_bounds__(TPB) void mmix_kernel(
    const ushortT* __restrict__ EaT,
    const float* __restrict__ W2x, const float* __restrict__ W2s,
    const float* __restrict__ X, const float* __restrict__ S,
    float* __restrict__ Xhat, float* __restrict__ Shat) {
  const int jt = blockIdx.x;   // 0..127
  const int br = blockIdx.y;   // 0..1
  const float* W2 = br ? W2s : W2x;
  const int j0 = jt * 16;
  const int tid = threadIdx.x;
  const int w = tid >> 6, lane = tid & 63;
  const int b = w;
  const int lj = tid & 15, kp0 = tid >> 4;
  const int fl = lane & 15, g = lane >> 4;
  __shared__ ushortT bpan[2][16][72];

  const size_t rb0 = ((size_t)(br * 4 + b) * 2 + 0) * 16;
  const size_t rb1 = ((size_t)(br * 4 + b) * 2 + 1) * 16;

  f32x4 acc0 = {0.f, 0.f, 0.f, 0.f};
  f32x4 acc1 = {0.f, 0.f, 0.f, 0.f};

  float r0, r1, r2, r3;
  r0 = W2[(size_t)(2 * kp0)      * KK + j0 + lj];
  r1 = W2[(size_t)(2 * kp0 + 1)  * KK + j0 + lj];
  r2 = W2[(size_t)(2 * kp0 + 32) * KK + j0 + lj];
  r3 = W2[(size_t)(2 * kp0 + 33) * KK + j0 + lj];

  for (int c = 0; c < 32; ++c) {
    const int cur = c & 1;
    unsigned int u0, u1;
    asm("v_cvt_pk_bf16_f32 %0, %1, %2" : "=v"(u0) : "v"(r0), "v"(r1));
    asm("v_cvt_pk_bf16_f32 %0, %1, %2" : "=v"(u1) : "v"(r2), "v"(r3));
    *(unsigned int*)(&bpan[cur][lj][kp0 * 2]) = u0;
    *(unsigned int*)(&bpan[cur][lj][(kp0 + 16) * 2]) = u1;
    __syncthreads();
    if (c < 31) {
      const int kc = (c + 1) * 64;
      r0 = W2[(size_t)(kc + 2 * kp0)      * KK + j0 + lj];
      r1 = W2[(size_t)(kc + 2 * kp0 + 1)  * KK + j0 + lj];
      r2 = W2[(size_t)(kc + 2 * kp0 + 32) * KK + j0 + lj];
      r3 = W2[(size_t)(kc + 2 * kp0 + 33) * KK + j0 + lj];
    }
#pragma unroll
    for (int s = 0; s < 2; ++s) {
      const int k = c * 64 + s * 32 + g * 8;
      short8v bf = *(const short8v*)(&bpan[cur][fl][s * 32 + g * 8]);
      short8v a0 = *(const short8v*)(EaT + (rb0 + fl) * (size_t)KK + k);
      short8v a1 = *(const short8v*)(EaT + (rb1 + fl) * (size_t)KK + k);
      acc0 = __builtin_amdgcn_mfma_f32_16x16x32_bf16(a0, bf, acc0, 0, 0, 0);
      acc1 = __builtin_amdgcn_mfma_f32_16x16x32_bf16(a1, bf, acc1, 0, 0, 0);
    }
    __syncthreads();
  }

  const int j = j0 + fl;
#pragma unroll
  for (int r = 0; r < 4; ++r) {
    const int l = g * 4 + r;
    if (br == 0) {
      float xv0 = X[(size_t)(b * 16 + l) * NN + 2 * j + 0];
      Xhat[((size_t)(b * 32 + l) * KK + j) * 2 + 0] = acc0[r] * xv0;
      Xhat[((size_t)(b * 32 + 16 + l) * KK + j) * 2 + 0] = xv0;
      float xv1 = X[(size_t)(b * 16 + l) * NN + 2 * j + 1];
      Xhat[((size_t)(b * 32 + l) * KK + j) * 2 + 1] = acc1[r] * xv1;
      Xhat[((size_t)(b * 32 + 16 + l) * KK + j) * 2 + 1] = xv1;
    } else {
      float pe0 = sinf((float)j), pe1 = cosf((float)j);
      float sv0 = S[(size_t)(b * 16 + l) * NN + 2 * j + 0];
      Shat[((size_t)(b * 32 + l) * KK + j) * 2 + 0] = fmaf(acc0[r], sv0, pe0);
      Shat[((size_t)(b * 32 + 16 + l) * KK + j) * 2 + 0] = sv0 + pe0;
      float sv1 = S[(size_t)(b * 16 + l) * NN + 2 * j + 1];
      Shat[((size_t)(b * 32 + l) * KK + j) * 2 + 1] = fmaf(acc1[r], sv1, pe1);
      Shat[((size_t)(b * 32 + 16 + l) * KK + j) * 2 + 1] = sv1 + pe1;
    }
  }
}

// ---------------------------------------------------------------- 3x3 SAME conv, H=2048 W=2
__global__ __launch_bounds__(TPB) void conv_kernel(
    const float* __restrict__ Xhat, const float* __restrict__ Shat,
    const float* __restrict__ Wx, const float* __restrict__ Bx,
    const float* __restrict__ Ws, const float* __restrict__ Bs,
    float* __restrict__ out) {
  const int kt = blockIdx.x;
  const int b = blockIdx.y;
  const int br = blockIdx.z;
  const float* In = (br ? Shat : Xhat) + (size_t)b * 32 * KK * 2;
  const float* Wt = br ? Ws : Wx;
  const float* Bi = br ? Bs : Bx;
  __shared__ float inT[32 * 66 * 2];
  __shared__ float wts[32 * 289];
  const int tid = threadIdx.x;
  const int k0 = kt * 64;

  for (int f = tid; f < 32 * 288; f += TPB) {
    const int c = f / 288, rem = f % 288;
    wts[c * 289 + rem] = Wt[f];
  }
  for (int f = tid; f < 32 * 66 * 2; f += TPB) {
    const int ch = f / 132, rem = f % 132;
    const int kk = rem >> 1, t = rem & 1;
    const int kg = k0 - 1 + kk;
    inT[f] = (kg >= 0 && kg < KK) ? In[((size_t)ch * KK + kg) * 2 + t] : 0.f;
  }
  __syncthreads();

  const int c = tid >> 3, sub = tid & 7;
  const float bias = Bi[c];
  float acc0[8], acc1[8];
#pragma unroll
  for (int i = 0; i < 8; ++i) { acc0[i] = bias; acc1[i] = bias; }

  for (int cin = 0; cin < 32; ++cin) {
    const float* wp = wts + c * 289 + cin * 9;
    const float w00 = wp[0], w01 = wp[1], w02 = wp[2];
    const float w10 = wp[3], w11 = wp[4], w12 = wp[5];
    const float w20 = wp[6], w21 = wp[7], w22 = wp[8];
    const float* ip = inT + cin * 132;
#pragma unroll
    for (int i = 0; i < 8; ++i) {
      const int kl = sub + 8 * i;
      const float* q = ip + kl * 2;
      const float i00 = q[0], i01 = q[1];
      const float i10 = q[2], i11 = q[3];
      const float i20 = q[4], i21 = q[5];
      acc0[i] = fmaf(i00, w01, acc0[i]); acc0[i] = fmaf(i01, w02, acc0[i]);
      acc0[i] = fmaf(i10, w11, acc0[i]); acc0[i] = fmaf(i11, w12, acc0[i]);
      acc0[i] = fmaf(i20, w21, acc0[i]); acc0[i] = fmaf(i21, w22, acc0[i]);
      acc1[i] = fmaf(i00, w00, acc1[i]); acc1[i] = fmaf(i01, w01, acc1[i]);
      acc1[i] = fmaf(i10, w10, acc1[i]); acc1[i] = fmaf(i11, w11, acc1[i]);
      acc1[i] = fmaf(i20, w20, acc1[i]); acc1[i] = fmaf(i21, w21, acc1[i]);
    }
  }
#pragma unroll
  for (int i = 0; i < 8; ++i) {
    const int k = k0 + sub + 8 * i;
    const size_t o = ((size_t)(b * 64 + br * 32 + c) * KK + k) * 2;
    out[o] = acc0[i];
    out[o + 1] = acc1[i];
  }
}

// ---------------------------------------------------------------- launch
extern "C" void kernel_launch(void* const* d_in, const int* in_sizes, int n_in,
                              void* d_out, int out_size, void* d_ws, size_t ws_size,
                              hipStream_t stream) {
  (void)in_sizes; (void)n_in; (void)out_size; (void)ws_size;
  const float* X   = (const float*)d_in[0];
  const float* S   = (const float*)d_in[1];
  const float* W1x = (const float*)d_in[2];
  const float* W1s = (const float*)d_in[3];
  const float* W2x = (const float*)d_in[4];
  const float* W2s = (const float*)d_in[5];
  const float* Cwx = (const float*)d_in[6];
  const float* Cbx = (const float*)d_in[7];
  const float* Cws = (const float*)d_in[8];
  const float* Cbs = (const float*)d_in[9];
  float* out = (float*)d_out;
  float* ws = (float*)d_ws;

  ushortT* Ehl = (ushortT*)(ws + OFF_EHL);
  ushortT* Ept = (ushortT*)(ws + OFF_ET);
  float*   lse = ws + OFF_LSE;
  ushortT* EaT = (ushortT*)(ws + OFF_EAT);
  float*   Xh  = ws + OFF_XH;
  float*   Sh  = ws + OFF_SH;

  hipLaunchKernelGGL(prep_kernel, dim3(16, NBATCH), dim3(TPB), 0, stream,
                     X, S, W1x, W1s, Ehl, Ept);
  hipLaunchKernelGGL(passA_kernel, dim3(1024), dim3(TPB), 0, stream,
                     Ehl, lse);
  hipLaunchKernelGGL(passB_kernel, dim3(1024), dim3(TPB), 0, stream,
                     Ehl, Ept, lse, EaT);
  hipLaunchKernelGGL(mmix_kernel, dim3(128, 2), dim3(TPB), 0, stream,
                     EaT, W2x, W2s, X, S, Xh, Sh);
  hipLaunchKernelGGL(conv_kernel, dim3(32, NBATCH, 2), dim3(TPB), 0, stream,
                     Xh, Sh, Cwx, Cbx, Cws, Cbs, out);
}